// Round 4
// baseline (271.329 us; speedup 1.0000x reference)
//
#include <hip/hip_runtime.h>
#include <hip/hip_bf16.h>

// z[e, :] = h[src[e], :] * h[dst[e], :]
// h: [50000, 64] f32 (12.8 MB), src/dst: [800000] int32, out: [800000, 64] f32 (204.8 MB)
//
// Round 1 lesson: one gather pair per thread = latency-bound (768 cyc/wave).
// This version: persistent grid (2000 blocks = ~31 waves/CU), each 16-thread
// edge-slot processes 25 edges in batches of 5 -> 10 independent gather loads
// in flight per thread. Non-temporal stores/index-loads keep h resident in L2.
//
// NOTE: __builtin_nontemporal_* requires a clang vector type, not HIP's
// float4 class -> use ext_vector_type(4).

#define D_FEAT 64
typedef float vf4 __attribute__((ext_vector_type(4)));

constexpr int BLOCK = 256;
constexpr int GRID  = 2000;
constexpr int SLOTS = GRID * BLOCK / 16;   // 32000 edge slots
constexpr int BATCH = 5;

__global__ __launch_bounds__(BLOCK) void hadamard_gather_kernel(
    const float* __restrict__ h,
    const int* __restrict__ src,
    const int* __restrict__ dst,
    float* __restrict__ out,
    int n_edges)
{
    int tid  = blockIdx.x * BLOCK + threadIdx.x;
    int slot = tid >> 4;       // edge slot
    int c    = tid & 15;       // float4 chunk within the 64-float row

    int iters = (n_edges - slot + SLOTS - 1) / SLOTS;   // edges this slot handles

    for (int it = 0; it < iters; it += BATCH) {
        int nb = (iters - it) < BATCH ? (iters - it) : BATCH;

        int e[BATCH], s[BATCH], d[BATCH];
        // 1) issue all index loads (independent, streamed once -> non-temporal)
        for (int j = 0; j < BATCH; ++j) {
            if (j < nb) {
                e[j] = slot + (it + j) * SLOTS;
                s[j] = __builtin_nontemporal_load(src + e[j]);
                d[j] = __builtin_nontemporal_load(dst + e[j]);
            }
        }
        // 2) issue all gathers (independent; want these cached in L2/L3)
        vf4 a[BATCH], b[BATCH];
        for (int j = 0; j < BATCH; ++j) {
            if (j < nb) {
                a[j] = reinterpret_cast<const vf4*>(h + (long long)s[j] * D_FEAT)[c];
                b[j] = reinterpret_cast<const vf4*>(h + (long long)d[j] * D_FEAT)[c];
            }
        }
        // 3) multiply + streaming store (never re-read -> non-temporal)
        for (int j = 0; j < BATCH; ++j) {
            if (j < nb) {
                vf4 r = a[j] * b[j];
                __builtin_nontemporal_store(
                    r, reinterpret_cast<vf4*>(out + (long long)e[j] * D_FEAT) + c);
            }
        }
    }
}

extern "C" void kernel_launch(void* const* d_in, const int* in_sizes, int n_in,
                              void* d_out, int out_size, void* d_ws, size_t ws_size,
                              hipStream_t stream) {
    const float* h   = reinterpret_cast<const float*>(d_in[0]);
    const int*   src = reinterpret_cast<const int*>(d_in[1]);
    const int*   dst = reinterpret_cast<const int*>(d_in[2]);
    float* out = reinterpret_cast<float*>(d_out);

    int n_edges = in_sizes[1];   // 800000

    hadamard_gather_kernel<<<GRID, BLOCK, 0, stream>>>(h, src, dst, out, n_edges);
}